// Round 1
// baseline (539.485 us; speedup 1.0000x reference)
//
#include <hip/hip_runtime.h>

// Problem dims (fixed by setup_inputs)
#define BN 16      // batch
#define FD 256     // features
#define SH 64      // small h
#define SW 64      // small w
#define BH 512     // big H
#define BW 512     // big W
#define KN 21      // classes
#define SP (SH*SW)   // 4096 small pixels
#define BP (BH*BW)   // 262144 big pixels

// ---------------------------------------------------------------------------
// Adjoint bilinear (align_corners=True) weight: contribution of big index
// `big` onto small index `small`. scale = (64-1)/(512-1) = 63/511.
// Additive accumulation handles the y1==y0 clamp at the top edge exactly.
// f64 so floor boundaries track the numpy float64 reference.
__device__ __forceinline__ float adj_w(int big, int small) {
    double t = (double)big * (63.0 / 511.0);
    int i0 = (int)t;                 // t >= 0 -> trunc == floor
    double fr = t - (double)i0;
    int i1 = i0 + 1; if (i1 > 63) i1 = 63;
    float w = 0.0f;
    if (i0 == small) w += (float)(1.0 - fr);
    if (i1 == small) w += (float)fr;
    return w;
}

__device__ __forceinline__ void adj_range(int small, int& lo, int& hi) {
    lo = (int)floorf((small - 1) * (511.0f / 63.0f)); if (lo < 0) lo = 0;
    hi = (int)ceilf((small + 1) * (511.0f / 63.0f));  if (hi > 511) hi = 511;
}

// ---------------------------------------------------------------------------
// K1: logits = einsum('bfhw,kf->bkhw') + bias, softmax over k -> seg_small
// one thread per (b, p); conv_w read with wave-uniform addresses (scalarizes)
__global__ __launch_bounds__(256) void k_seg(const float* __restrict__ fm,
                                             const float* __restrict__ cw,
                                             const float* __restrict__ cb,
                                             float* __restrict__ seg) {
    int gid = blockIdx.x * 256 + threadIdx.x;     // b*SP + p
    int b = gid >> 12;
    int p = gid & (SP - 1);
    const float* fmb = fm + (size_t)b * FD * SP + p;

    float acc[KN];
#pragma unroll
    for (int k = 0; k < KN; ++k) acc[k] = 0.0f;

#pragma unroll 4
    for (int f = 0; f < FD; ++f) {
        float v = fmb[(size_t)f * SP];
#pragma unroll
        for (int k = 0; k < KN; ++k)
            acc[k] = fmaf(v, cw[k * FD + f], acc[k]);
    }

    float mx = -1e30f;
#pragma unroll
    for (int k = 0; k < KN; ++k) { acc[k] += cb[k]; mx = fmaxf(mx, acc[k]); }
    float s = 0.0f;
#pragma unroll
    for (int k = 0; k < KN; ++k) { acc[k] = expf(acc[k] - mx); s += acc[k]; }
    float inv = 1.0f / s;

    float* segb = seg + (size_t)b * KN * SP + p;
#pragma unroll
    for (int k = 0; k < KN; ++k) segb[(size_t)k * SP] = acc[k] * inv;
}

// ---------------------------------------------------------------------------
// K2a: adjoint-downsample along X: tmpA[bc, Y, s] = sum_X W[X,s] * x[bc, Y, X]
__global__ __launch_bounds__(256) void k_downx(const float* __restrict__ x,
                                               float* __restrict__ tmpA) {
    int gid = blockIdx.x * 256 + threadIdx.x;   // ((bc)*BH + Y)*SW + s
    int s  = gid & 63;
    int Y  = (gid >> 6) & 511;
    int bc = gid >> 15;                          // 0..47
    const float* row = x + ((size_t)bc * BH + Y) * BW;
    int lo, hi; adj_range(s, lo, hi);
    float acc = 0.0f;
    for (int X = lo; X <= hi; ++X) acc = fmaf(adj_w(X, s), row[X], acc);
    tmpA[gid] = acc;
}

// K2b: adjoint-downsample along Y: xd[bc, r, s] = sum_Y W[Y,r] * tmpA[bc, Y, s]
__global__ __launch_bounds__(256) void k_downy(const float* __restrict__ tmpA,
                                               float* __restrict__ xd) {
    int gid = blockIdx.x * 256 + threadIdx.x;   // ((bc)*SH + r)*SW + s
    int s  = gid & 63;
    int r  = (gid >> 6) & 63;
    int bc = gid >> 12;                          // 0..47
    const float* base = tmpA + (size_t)bc * BH * SW + s;
    int lo, hi; adj_range(r, lo, hi);
    float acc = 0.0f;
    for (int Y = lo; Y <= hi; ++Y) acc = fmaf(adj_w(Y, r), base[(size_t)Y * SW], acc);
    xd[gid] = acc;
}

// ---------------------------------------------------------------------------
// K3: q[b,k,c] = (1/(BH*BW)) * sum_p seg[b,k,p] * xd[b,c,p]
// one block per (b,k)
__global__ __launch_bounds__(256) void k_q(const float* __restrict__ seg,
                                           const float* __restrict__ xd,
                                           float* __restrict__ q) {
    int b = blockIdx.x / KN, k = blockIdx.x % KN;
    const float* sg = seg + ((size_t)b * KN + k) * SP;
    const float* xb = xd + (size_t)b * 3 * SP;
    float a0 = 0.f, a1 = 0.f, a2 = 0.f;
    for (int p = threadIdx.x; p < SP; p += 256) {
        float sv = sg[p];
        a0 = fmaf(sv, xb[p], a0);
        a1 = fmaf(sv, xb[SP + p], a1);
        a2 = fmaf(sv, xb[2 * SP + p], a2);
    }
    __shared__ float red[3][256];
    red[0][threadIdx.x] = a0; red[1][threadIdx.x] = a1; red[2][threadIdx.x] = a2;
    __syncthreads();
    for (int off = 128; off > 0; off >>= 1) {
        if (threadIdx.x < (unsigned)off) {
            red[0][threadIdx.x] += red[0][threadIdx.x + off];
            red[1][threadIdx.x] += red[1][threadIdx.x + off];
            red[2][threadIdx.x] += red[2][threadIdx.x + off];
        }
        __syncthreads();
    }
    if (threadIdx.x == 0) {
        const float scale = 1.0f / (float)BP;
        float* qo = q + ((size_t)b * KN + k) * 3;
        qo[0] = red[0][0] * scale;
        qo[1] = red[1][0] * scale;
        qo[2] = red[2][0] * scale;
    }
}

// ---------------------------------------------------------------------------
// K4: attn[b,k,p] = sum_c x[b,c,p] * q[b,k,c]   (float4 over pixels)
__global__ __launch_bounds__(256) void k_attn(const float* __restrict__ x,
                                              const float* __restrict__ q,
                                              float* __restrict__ out) {
    __shared__ float qs[KN * 3];
    int b   = blockIdx.x >> 8;        // 256 blocks per batch
    int blk = blockIdx.x & 255;
    if (threadIdx.x < KN * 3) qs[threadIdx.x] = q[(size_t)b * KN * 3 + threadIdx.x];
    __syncthreads();

    int p4 = blk * 256 + threadIdx.x;            // float4 pixel index, 0..65535
    const float4* xb = (const float4*)(x + (size_t)b * 3 * BP);
    float4 x0 = xb[p4];
    float4 x1 = xb[BP / 4 + p4];
    float4 x2 = xb[2 * (BP / 4) + p4];
    float4* ob = (float4*)(out + (size_t)b * KN * BP) + p4;
#pragma unroll
    for (int k = 0; k < KN; ++k) {
        float q0 = qs[k * 3], q1 = qs[k * 3 + 1], q2 = qs[k * 3 + 2];
        float4 r;
        r.x = fmaf(x0.x, q0, fmaf(x1.x, q1, x2.x * q2));
        r.y = fmaf(x0.y, q0, fmaf(x1.y, q1, x2.y * q2));
        r.z = fmaf(x0.z, q0, fmaf(x1.z, q1, x2.z * q2));
        r.w = fmaf(x0.w, q0, fmaf(x1.w, q1, x2.w * q2));
        ob[(size_t)k * (BP / 4)] = r;
    }
}

// ---------------------------------------------------------------------------
extern "C" void kernel_launch(void* const* d_in, const int* in_sizes, int n_in,
                              void* d_out, int out_size, void* d_ws, size_t ws_size,
                              hipStream_t stream) {
    const float* fm = (const float*)d_in[0];   // [16,256,64,64]
    const float* x  = (const float*)d_in[1];   // [16,3,512,512]
    const float* cw = (const float*)d_in[2];   // [21,256]
    const float* cb = (const float*)d_in[3];   // [21]
    float* out = (float*)d_out;                // [16,21,512,512]

    // workspace layout (floats): seg | tmpA | xd | q  (~12.6 MB total)
    float* seg  = (float*)d_ws;                       // 16*21*4096
    float* tmpA = seg  + (size_t)BN * KN * SP;        // 16*3*512*64
    float* xd   = tmpA + (size_t)BN * 3 * BH * SW;    // 16*3*4096
    float* q    = xd   + (size_t)BN * 3 * SP;         // 16*21*3

    k_seg  <<<BN * SP / 256,            256, 0, stream>>>(fm, cw, cb, seg);
    k_downx<<<BN * 3 * BH * SW / 256,   256, 0, stream>>>(x, tmpA);
    k_downy<<<BN * 3 * SP / 256,        256, 0, stream>>>(tmpA, xd);
    k_q    <<<BN * KN,                  256, 0, stream>>>(seg, xd, q);
    k_attn <<<BN * (BP / 1024),         256, 0, stream>>>(x, q, out);
}

// Round 2
// 510.887 us; speedup vs baseline: 1.0560x; 1.0560x over previous
//
#include <hip/hip_runtime.h>

// Problem dims (fixed by setup_inputs)
#define BN 16      // batch
#define FD 256     // features
#define SH 64      // small h
#define SW 64      // small w
#define BH 512     // big H
#define BW 512     // big W
#define KN 21      // classes
#define SP (SH*SW)   // 4096 small pixels
#define BP (BH*BW)   // 262144 big pixels

#define SEG_BLOCKS 64                      // 16384 threads, 4 px each
#define DOWNX_BLOCKS (BN*3*BH*SW/256)      // 6144

typedef float f32x4 __attribute__((ext_vector_type(4)));

// ---------------------------------------------------------------------------
// Adjoint bilinear (align_corners=True) weight: contribution of big index
// `big` onto small index `small`. scale = 63/511. f64 for exact floor edges.
__device__ __forceinline__ float adj_w(int big, int small) {
    double t = (double)big * (63.0 / 511.0);
    int i0 = (int)t;
    double fr = t - (double)i0;
    int i1 = i0 + 1; if (i1 > 63) i1 = 63;
    float w = 0.0f;
    if (i0 == small) w += (float)(1.0 - fr);
    if (i1 == small) w += (float)fr;
    return w;
}

__device__ __forceinline__ void adj_range(int small, int& lo, int& hi) {
    lo = (int)floorf((small - 1) * (511.0f / 63.0f)); if (lo < 0) lo = 0;
    hi = (int)ceilf((small + 1) * (511.0f / 63.0f));  if (hi > 511) hi = 511;
}

// ---------------------------------------------------------------------------
// seg: 1x1 conv + softmax, 4 pixels (one float4) per thread
__device__ __forceinline__ void seg_body(int blk, int tid,
                                         const float* __restrict__ fm,
                                         const float* __restrict__ cw,
                                         const float* __restrict__ cb,
                                         float* __restrict__ seg) {
    int gid = blk * 256 + tid;          // 0..16383
    int b   = gid >> 10;                // 1024 float4-groups per batch
    int p4  = gid & 1023;
    const f32x4* fmb = (const f32x4*)(fm + (size_t)b * FD * SP) + p4;

    f32x4 acc[KN];
#pragma unroll
    for (int k = 0; k < KN; ++k) acc[k] = (f32x4)0.0f;

#pragma unroll 2
    for (int f = 0; f < FD; ++f) {
        f32x4 v = fmb[f * (SP / 4)];
#pragma unroll
        for (int k = 0; k < KN; ++k)
            acc[k] += v * cw[k * FD + f];
    }

    f32x4 mx = (f32x4)(-1e30f);
#pragma unroll
    for (int k = 0; k < KN; ++k) {
        acc[k] += cb[k];
        mx.x = fmaxf(mx.x, acc[k].x); mx.y = fmaxf(mx.y, acc[k].y);
        mx.z = fmaxf(mx.z, acc[k].z); mx.w = fmaxf(mx.w, acc[k].w);
    }
    f32x4 s = (f32x4)0.0f;
#pragma unroll
    for (int k = 0; k < KN; ++k) {
        acc[k].x = expf(acc[k].x - mx.x); acc[k].y = expf(acc[k].y - mx.y);
        acc[k].z = expf(acc[k].z - mx.z); acc[k].w = expf(acc[k].w - mx.w);
        s += acc[k];
    }
    f32x4 inv;
    inv.x = 1.0f / s.x; inv.y = 1.0f / s.y; inv.z = 1.0f / s.z; inv.w = 1.0f / s.w;

    f32x4* segb = (f32x4*)(seg + (size_t)b * KN * SP) + p4;
#pragma unroll
    for (int k = 0; k < KN; ++k) segb[k * (SP / 4)] = acc[k] * inv;
}

// downx: tmpA[bc, Y, s] = sum_X W[X,s] * x[bc, Y, X]
__device__ __forceinline__ void downx_body(int blk, int tid,
                                           const float* __restrict__ x,
                                           float* __restrict__ tmpA) {
    int gid = blk * 256 + tid;       // ((bc)*BH + Y)*SW + s
    int s  = gid & 63;
    int Y  = (gid >> 6) & 511;
    int bc = gid >> 15;              // 0..47
    const float* row = x + ((size_t)bc * BH + Y) * BW;
    int lo, hi; adj_range(s, lo, hi);
    float acc = 0.0f;
    for (int X = lo; X <= hi; ++X) acc = fmaf(adj_w(X, s), row[X], acc);
    tmpA[gid] = acc;
}

// Phase 1: seg (blocks [0,64)) runs concurrently with downx (blocks [64,6208))
__global__ __launch_bounds__(256) void k_phase1(const float* __restrict__ fm,
                                                const float* __restrict__ cw,
                                                const float* __restrict__ cb,
                                                const float* __restrict__ x,
                                                float* __restrict__ seg,
                                                float* __restrict__ tmpA) {
    if (blockIdx.x < SEG_BLOCKS) seg_body(blockIdx.x, threadIdx.x, fm, cw, cb, seg);
    else                         downx_body(blockIdx.x - SEG_BLOCKS, threadIdx.x, x, tmpA);
}

// ---------------------------------------------------------------------------
// downy: xd[bc, r, s] = sum_Y W[Y,r] * tmpA[bc, Y, s]
__global__ __launch_bounds__(256) void k_downy(const float* __restrict__ tmpA,
                                               float* __restrict__ xd) {
    int gid = blockIdx.x * 256 + threadIdx.x;   // ((bc)*SH + r)*SW + s
    int s  = gid & 63;
    int r  = (gid >> 6) & 63;
    int bc = gid >> 12;                          // 0..47
    const float* base = tmpA + (size_t)bc * BH * SW + s;
    int lo, hi; adj_range(r, lo, hi);
    float acc = 0.0f;
    for (int Y = lo; Y <= hi; ++Y) acc = fmaf(adj_w(Y, r), base[(size_t)Y * SW], acc);
    xd[gid] = acc;
}

// ---------------------------------------------------------------------------
// q[b,k,c] = (1/BP) * sum_p seg[b,k,p] * xd[b,c,p]; one block per (b,k)
__global__ __launch_bounds__(256) void k_q(const float* __restrict__ seg,
                                           const float* __restrict__ xd,
                                           float* __restrict__ q) {
    int b = blockIdx.x / KN, k = blockIdx.x % KN;
    const float* sg = seg + ((size_t)b * KN + k) * SP;
    const float* xb = xd + (size_t)b * 3 * SP;
    float a0 = 0.f, a1 = 0.f, a2 = 0.f;
    for (int p = threadIdx.x; p < SP; p += 256) {
        float sv = sg[p];
        a0 = fmaf(sv, xb[p], a0);
        a1 = fmaf(sv, xb[SP + p], a1);
        a2 = fmaf(sv, xb[2 * SP + p], a2);
    }
    __shared__ float red[3][256];
    red[0][threadIdx.x] = a0; red[1][threadIdx.x] = a1; red[2][threadIdx.x] = a2;
    __syncthreads();
    for (int off = 128; off > 0; off >>= 1) {
        if (threadIdx.x < (unsigned)off) {
            red[0][threadIdx.x] += red[0][threadIdx.x + off];
            red[1][threadIdx.x] += red[1][threadIdx.x + off];
            red[2][threadIdx.x] += red[2][threadIdx.x + off];
        }
        __syncthreads();
    }
    if (threadIdx.x == 0) {
        const float scale = 1.0f / (float)BP;
        float* qo = q + ((size_t)b * KN + k) * 3;
        qo[0] = red[0][0] * scale;
        qo[1] = red[1][0] * scale;
        qo[2] = red[2][0] * scale;
    }
}

// ---------------------------------------------------------------------------
// attn[b,k,p] = sum_c x[b,c,p] * q[b,k,c]; float4, nontemporal stores
__global__ __launch_bounds__(256) void k_attn(const float* __restrict__ x,
                                              const float* __restrict__ q,
                                              float* __restrict__ out) {
    int b   = blockIdx.x >> 8;
    int blk = blockIdx.x & 255;
    int p4  = blk * 256 + threadIdx.x;

    const f32x4* xb = (const f32x4*)(x + (size_t)b * 3 * BP);
    f32x4 x0 = xb[p4];
    f32x4 x1 = xb[BP / 4 + p4];
    f32x4 x2 = xb[2 * (BP / 4) + p4];

    __shared__ float qs[KN * 3];
    if (threadIdx.x < KN * 3) qs[threadIdx.x] = q[(size_t)b * KN * 3 + threadIdx.x];
    __syncthreads();

    f32x4* ob = (f32x4*)(out + (size_t)b * KN * BP) + p4;
#pragma unroll
    for (int k = 0; k < KN; ++k) {
        float q0 = qs[k * 3], q1 = qs[k * 3 + 1], q2 = qs[k * 3 + 2];
        f32x4 r = x0 * q0 + x1 * q1 + x2 * q2;
        __builtin_nontemporal_store(r, ob + (size_t)k * (BP / 4));
    }
}

// ---------------------------------------------------------------------------
extern "C" void kernel_launch(void* const* d_in, const int* in_sizes, int n_in,
                              void* d_out, int out_size, void* d_ws, size_t ws_size,
                              hipStream_t stream) {
    const float* fm = (const float*)d_in[0];   // [16,256,64,64]
    const float* x  = (const float*)d_in[1];   // [16,3,512,512]
    const float* cw = (const float*)d_in[2];   // [21,256]
    const float* cb = (const float*)d_in[3];   // [21]
    float* out = (float*)d_out;                // [16,21,512,512]

    // workspace layout (floats): seg | tmpA | xd | q  (~12.6 MB total)
    float* seg  = (float*)d_ws;                       // 16*21*4096
    float* tmpA = seg  + (size_t)BN * KN * SP;        // 16*3*512*64
    float* xd   = tmpA + (size_t)BN * 3 * BH * SW;    // 16*3*4096
    float* q    = xd   + (size_t)BN * 3 * SP;         // 16*21*3

    k_phase1<<<SEG_BLOCKS + DOWNX_BLOCKS, 256, 0, stream>>>(fm, cw, cb, x, seg, tmpA);
    k_downy <<<BN * 3 * SP / 256,         256, 0, stream>>>(tmpA, xd);
    k_q     <<<BN * KN,                   256, 0, stream>>>(seg, xd, q);
    k_attn  <<<BN * (BP / 1024),          256, 0, stream>>>(x, q, out);
}